// Round 2
// baseline (8721.015 us; speedup 1.0000x reference)
//
#include <hip/hip_runtime.h>

// ---------------- problem dims ----------------
#define S_LEN 128
#define BATCH 64
#define EDIM  512
#define PLEN  160
#define PDIM  512
#define HDIM  1024
#define G3    3072      // 3*H
#define NBLK  128       // 64 gate blocks + 64 attention blocks
#define NTHR  256

typedef _Float16 half8v  __attribute__((ext_vector_type(8)));
typedef _Float16 half4v  __attribute__((ext_vector_type(4)));
typedef _Float16 half2v  __attribute__((ext_vector_type(2)));
typedef float    f32x4   __attribute__((ext_vector_type(4)));

// ---------------- workspace layout (bytes) ----------------
// ctrl: arrive flags, 128 slots @ stride 32 uints (one cache line each)
#define CTRL_UINTS 24576
#define OFF_CTRL ((size_t)0)                                  // 96 KiB
#define OFF_WIH  ((size_t)(CTRL_UINTS*4))                     // fp16 [3072][1024]
#define OFF_WHH  (OFF_WIH  + (size_t)G3*HDIM*2)               // fp16 [3072][1024]
#define OFF_WQT  (OFF_WHH  + (size_t)G3*HDIM*2)               // fp16 [1024][512]  (wq transposed)
#define OFF_INC  (OFF_WQT  + (size_t)HDIM*PDIM*2)             // fp16 [128][64][512]
#define OFF_POST (OFF_INC  + (size_t)S_LEN*BATCH*EDIM*2)      // fp16 [160][64][512]
#define OFF_PWQ  (OFF_POST + (size_t)PLEN*BATCH*PDIM*2)       // f32  [160*64][1024]  post@wqT (fp32: precision)
#define OFF_PB   (OFF_PWQ  + (size_t)PLEN*BATCH*HDIM*4)       // f32  [160*64]        post@bq
#define OFF_HH   (OFF_PB   + (size_t)PLEN*BATCH*4)            // fp16 [64][1024]
#define OFF_CTX  (OFF_HH   + (size_t)BATCH*HDIM*2)            // fp16 [64][512]
// total ~71 MB

__global__ void init_ctrl(unsigned* u) {
    int i = threadIdx.x + blockIdx.x * blockDim.x;
    if (i < CTRL_UINTS) u[i] = 0u;
}

__device__ __forceinline__ float wave_sum(float v) {
    v += __shfl_xor(v, 32); v += __shfl_xor(v, 16); v += __shfl_xor(v, 8);
    v += __shfl_xor(v, 4);  v += __shfl_xor(v, 2);  v += __shfl_xor(v, 1);
    return v;
}
__device__ __forceinline__ float wave_max(float v) {
    v = fmaxf(v, __shfl_xor(v, 32)); v = fmaxf(v, __shfl_xor(v, 16));
    v = fmaxf(v, __shfl_xor(v, 8));  v = fmaxf(v, __shfl_xor(v, 4));
    v = fmaxf(v, __shfl_xor(v, 2));  v = fmaxf(v, __shfl_xor(v, 1));
    return v;
}

// One-hop grid barrier: every block release-stores its padded flag, then 128
// threads of every block each poll one flag directly (no central aggregator,
// no broadcast hop). Per-thread ACQUIRE on the observed flag provides the
// needed L1/L2 invalidate before post-barrier reads.
__device__ __forceinline__ void gbar(unsigned* arrive, unsigned& gen, int tid, int blk) {
    gen++;
    __syncthreads();   // compiler drains vmcnt before s_barrier -> all block stores in L2
    if (tid == 0)
        __hip_atomic_store(&arrive[blk * 32], gen, __ATOMIC_RELEASE, __HIP_MEMORY_SCOPE_AGENT);
    if (tid < NBLK) {
        unsigned* fl = &arrive[tid * 32];
        while (__hip_atomic_load(fl, __ATOMIC_RELAXED, __HIP_MEMORY_SCOPE_AGENT) < gen)
            __builtin_amdgcn_s_sleep(1);
        __hip_atomic_load(fl, __ATOMIC_ACQUIRE, __HIP_MEMORY_SCOPE_AGENT);
    }
    __syncthreads();
}

// one 16x16 output tile accumulation: D[m,n] += sum_k A[m,k] * W[n,k]
__device__ __forceinline__ void mfma_acc(f32x4& acc, const _Float16* __restrict__ A, int lda,
                                         const _Float16* __restrict__ Bb, int ldb,
                                         int ksteps, int lane) {
    const _Float16* ap = A  + (size_t)(lane & 15) * lda + ((lane >> 4) << 3);
    const _Float16* bp = Bb + (size_t)(lane & 15) * ldb + ((lane >> 4) << 3);
    #pragma unroll
    for (int ks = 0; ks < ksteps; ++ks) {
        half8v av = *(const half8v*)ap;
        half8v bv = *(const half8v*)bp;
        acc = __builtin_amdgcn_mfma_f32_16x16x32_f16(av, bv, acc, 0, 0, 0);
        ap += 32; bp += 32;
    }
}

// three output tiles sharing one A stream (r,z,n gate rows): halves load count
__device__ __forceinline__ void mfma_acc3(f32x4& a0, f32x4& a1, f32x4& a2,
        const _Float16* __restrict__ A, int lda,
        const _Float16* __restrict__ B0, const _Float16* __restrict__ B1,
        const _Float16* __restrict__ B2, int ldb, int ksteps, int lane) {
    const _Float16* ap = A  + (size_t)(lane & 15) * lda + ((lane >> 4) << 3);
    const _Float16* p0 = B0 + (size_t)(lane & 15) * ldb + ((lane >> 4) << 3);
    const _Float16* p1 = B1 + (size_t)(lane & 15) * ldb + ((lane >> 4) << 3);
    const _Float16* p2 = B2 + (size_t)(lane & 15) * ldb + ((lane >> 4) << 3);
    #pragma unroll
    for (int ks = 0; ks < ksteps; ++ks) {
        half8v av = *(const half8v*)ap;
        a0 = __builtin_amdgcn_mfma_f32_16x16x32_f16(av, *(const half8v*)p0, a0, 0, 0, 0);
        a1 = __builtin_amdgcn_mfma_f32_16x16x32_f16(av, *(const half8v*)p1, a1, 0, 0, 0);
        a2 = __builtin_amdgcn_mfma_f32_16x16x32_f16(av, *(const half8v*)p2, a2, 0, 0, 0);
        ap += 32; p0 += 32; p1 += 32; p2 += 32;
    }
}

__global__ __launch_bounds__(NTHR, 1) void gru_main(
    const float* __restrict__ incoming, const float* __restrict__ post,
    const float* __restrict__ h_init,   const float* __restrict__ w_ih,
    const float* __restrict__ w_hh,     const float* __restrict__ b_ih,
    const float* __restrict__ b_hh,     const float* __restrict__ wq,
    const float* __restrict__ bq,       const int* __restrict__ length,
    const int* __restrict__ post_length, float* __restrict__ out,
    char* __restrict__ ws)
{
    const int tid  = threadIdx.x;
    const int blk  = blockIdx.x;
    const int lane = tid & 63;
    const int wv   = tid >> 6;

    unsigned* arrive = (unsigned*)(ws + OFF_CTRL);
    _Float16* wih_h  = (_Float16*)(ws + OFF_WIH);
    _Float16* whh_h  = (_Float16*)(ws + OFF_WHH);
    _Float16* wqT_h  = (_Float16*)(ws + OFF_WQT);
    _Float16* inc_h  = (_Float16*)(ws + OFF_INC);
    _Float16* post_h = (_Float16*)(ws + OFF_POST);
    float*    pwq    = (float*)(ws + OFF_PWQ);
    float*    pbias  = (float*)(ws + OFF_PB);
    _Float16* h_h    = (_Float16*)(ws + OFF_HH);
    _Float16* ctx_h  = (_Float16*)(ws + OFF_CTX);

    __shared__ _Float16 s_h[HDIM];        // 2 KB: this batch's h row
    __shared__ float s_scores[PLEN];
    __shared__ float s_w[PLEN];
    __shared__ float s_bc[2];
    __shared__ float s_tr[32][33];        // wq transpose tile (init only)

    unsigned gen = 0;

    // ---------------- per-block loop-invariant hoists ----------------
    float bsr = 0.f, bsz = 0.f, bin_ = 0.f, bhn = 0.f;
    float hp[4] = {0.f, 0.f, 0.f, 0.f};
    int lenb[4] = {0, 0, 0, 0};
    int j0 = 0, ab = 0, plen = 0;
    if (blk < 64) {                       // gate block: owns h-cols j0..j0+15
        j0 = blk * 16;
        const int j = j0 + (lane & 15);
        bsr  = b_ih[j] + b_hh[j];
        bsz  = b_ih[HDIM + j] + b_hh[HDIM + j];
        bin_ = b_ih[2*HDIM + j];
        bhn  = b_hh[2*HDIM + j];
        const float hi = h_init[j];
        const int r0 = wv*16 + ((lane >> 4) << 2);
        #pragma unroll
        for (int r = 0; r < 4; ++r) { hp[r] = hi; lenb[r] = length[r0 + r]; }
    } else {                              // attention block: owns batch ab
        ab = blk - 64;
        plen = post_length[ab];
    }

    // ---------------- init phase 1: fp32 -> fp16 conversions ----------------
    {
        const int NV4_W    = G3*HDIM/4;
        const int NV4_INC  = S_LEN*BATCH*EDIM/4;
        const int NV4_POST = PLEN*BATCH*PDIM/4;
        const int TOT = 2*NV4_W + NV4_INC + NV4_POST;
        for (int i = blk*NTHR + tid; i < TOT; i += NBLK*NTHR) {
            const float* s; _Float16* dp; int o;
            if (i < NV4_W)                  { s = w_ih;     dp = wih_h;  o = i; }
            else if (i < 2*NV4_W)           { s = w_hh;     dp = whh_h;  o = i - NV4_W; }
            else if (i < 2*NV4_W + NV4_INC) { s = incoming; dp = inc_h;  o = i - 2*NV4_W; }
            else                            { s = post;     dp = post_h; o = i - 2*NV4_W - NV4_INC; }
            f32x4 v = *(const f32x4*)(s + (size_t)o*4);
            half4v hv4 = {(_Float16)v.x, (_Float16)v.y, (_Float16)v.z, (_Float16)v.w};
            *(half4v*)(dp + (size_t)o*4) = hv4;
        }
        for (int i = blk*NTHR + tid; i < BATCH*HDIM; i += NBLK*NTHR)
            h_h[i] = (_Float16)h_init[i & (HDIM-1)];
        // wq [512][1024] f32 -> wqT [1024][512] fp16 via LDS tile transpose
        for (int tile = blk; tile < 32*16; tile += NBLK) {
            const int jt = tile >> 4, dt = tile & 15;
            #pragma unroll
            for (int pass = 0; pass < 4; ++pass) {
                const int dd = (tid >> 5) + pass*8, jj = tid & 31;
                s_tr[dd][jj] = wq[(size_t)(dt*32 + dd)*HDIM + jt*32 + jj];
            }
            __syncthreads();
            #pragma unroll
            for (int pass = 0; pass < 4; ++pass) {
                const int jj2 = (tid >> 5) + pass*8, dd2 = tid & 31;
                wqT_h[(size_t)(jt*32 + jj2)*PDIM + dt*32 + dd2] = (_Float16)s_tr[dd2][jj2];
            }
            __syncthreads();
        }
    }
    gbar(arrive, gen, tid, blk);

    // ---- init phase 2: fold wq into post (postWQ = post @ wqT in f32, pbias = post @ bq) ----
    {
        const int NJOBS = (PLEN*BATCH/16) * (HDIM/16);    // 640 x 64 tiles
        for (int job = blk*4 + wv; job < NJOBS; job += NBLK*4) {
            const int mt = job >> 6, nt = job & 63;
            f32x4 acc = {0.f, 0.f, 0.f, 0.f};
            mfma_acc(acc, post_h + (size_t)mt*16*PDIM, PDIM,
                     wqT_h + (size_t)nt*16*PDIM, PDIM, PDIM/32, lane);
            const int m0 = mt*16 + ((lane >> 4) << 2);
            const int n  = nt*16 + (lane & 15);
            #pragma unroll
            for (int r = 0; r < 4; ++r)
                pwq[(size_t)(m0 + r)*HDIM + n] = acc[r];    // f32 store: no output rounding
        }
        for (int row = blk*4 + wv; row < PLEN*BATCH; row += NBLK*4) {
            const _Float16* pr = post_h + (size_t)row*PDIM + lane*8;
            float s = 0.f;
            #pragma unroll
            for (int jj = 0; jj < 8; ++jj) s += (float)pr[jj] * bq[lane*8 + jj];
            s = wave_sum(s);
            if (lane == 0) pbias[row] = s;
        }
    }
    gbar(arrive, gen, tid, blk);

    // ---------------- time loop: 2 grid barriers per step ----------------
    for (int t = 0; t < S_LEN; ++t) {
        f32x4 ghr = {0.f,0.f,0.f,0.f}, ghz = {0.f,0.f,0.f,0.f}, ghn_ = {0.f,0.f,0.f,0.f};
        f32x4 gir = {0.f,0.f,0.f,0.f}, giz = {0.f,0.f,0.f,0.f}, gin_ = {0.f,0.f,0.f,0.f};

        if (blk < 64) {
            // ==== P1 gate: gh = h@Whh^T (r,z,n) and gix = x_t@Wih[:, :512]^T ====
            // accumulators stay in registers across the barrier (no gacc/ghn buffers)
            mfma_acc3(ghr, ghz, ghn_, h_h + (size_t)(wv*16)*HDIM, HDIM,
                      whh_h + (size_t)j0*HDIM,
                      whh_h + (size_t)(HDIM + j0)*HDIM,
                      whh_h + (size_t)(2*HDIM + j0)*HDIM, HDIM, HDIM/32, lane);
            mfma_acc3(gir, giz, gin_, inc_h + ((size_t)t*BATCH + wv*16)*EDIM, EDIM,
                      wih_h + (size_t)j0*HDIM,
                      wih_h + (size_t)(HDIM + j0)*HDIM,
                      wih_h + (size_t)(2*HDIM + j0)*HDIM, HDIM, EDIM/32, lane);
        } else {
            // ==== P1 attention for batch ab: scores = postWQ . h, softmax, ctx ====
            if (tid < HDIM/8)
                *(half8v*)&s_h[tid*8] = *(const half8v*)&h_h[(size_t)ab*HDIM + tid*8];
            __syncthreads();
            float hf[16];
            #pragma unroll
            for (int i = 0; i < 16; ++i) hf[i] = (float)s_h[lane*16 + i];
            #pragma unroll 2
            for (int p = wv; p < PLEN; p += 4) {
                const float* rowp = pwq + ((size_t)p*BATCH + ab)*HDIM + lane*16;
                const f32x4 a0 = *(const f32x4*)rowp;
                const f32x4 a1 = *(const f32x4*)(rowp + 4);
                const f32x4 a2 = *(const f32x4*)(rowp + 8);
                const f32x4 a3 = *(const f32x4*)(rowp + 12);
                float sd = 0.f;
                #pragma unroll
                for (int jj = 0; jj < 4; ++jj)
                    sd += a0[jj]*hf[jj] + a1[jj]*hf[4+jj] + a2[jj]*hf[8+jj] + a3[jj]*hf[12+jj];
                sd = wave_sum(sd);
                if (lane == 0) s_scores[p] = sd + pbias[(size_t)p*BATCH + ab];
            }
            __syncthreads();
            if (wv == 0) {
                float m = -1e30f;
                for (int p = lane; p < plen; p += 64) m = fmaxf(m, s_scores[p]);
                m = wave_max(m);
                if (lane == 0) s_bc[0] = m;
            }
            __syncthreads();
            const float mx = s_bc[0];
            if (tid < PLEN) s_w[tid] = (tid < plen) ? __expf(s_scores[tid] - mx) : 0.f;
            __syncthreads();
            if (wv == 0) {
                float ss = 0.f;
                for (int p = lane; p < PLEN; p += 64) ss += s_w[p];
                ss = wave_sum(ss);
                if (lane == 0) s_bc[1] = 1.f / ss;
            }
            __syncthreads();
            const float inv_den = s_bc[1];
            // ctx[d0,d0+1] with a 16-deep register prefetch pipeline over p
            const int d0 = tid << 1;
            const _Float16* pcol = post_h + (size_t)ab*PDIM + d0;
            const size_t pstr = (size_t)BATCH*PDIM;
            half2v pref[16];
            #pragma unroll
            for (int i = 0; i < 16; ++i) pref[i] = *(const half2v*)(pcol + (size_t)i*pstr);
            float ca = 0.f, cb = 0.f;
            const int pend = ((plen + 15) >> 4) << 4;
            for (int base = 0; base < pend; base += 16) {
                #pragma unroll
                for (int i = 0; i < 16; ++i) {
                    const half2v cur = pref[i];
                    const int nx = base + 16 + i;
                    if (nx < PLEN) pref[i] = *(const half2v*)(pcol + (size_t)nx*pstr);
                    const float wp = s_w[base + i];
                    ca += wp * (float)cur[0];
                    cb += wp * (float)cur[1];
                }
            }
            half2v cv; cv[0] = (_Float16)(ca * inv_den); cv[1] = (_Float16)(cb * inv_den);
            *(half2v*)&ctx_h[(size_t)ab*PDIM + d0] = cv;
        }
        gbar(arrive, gen, tid, blk);   // barrier W: ctx ready

        if (blk < 64) {
            // ==== P2 gate: gi += ctx@Wih[:, 512:]^T, gate math, h update ====
            mfma_acc3(gir, giz, gin_, ctx_h + (size_t)(wv*16)*PDIM, PDIM,
                      wih_h + (size_t)j0*HDIM + PDIM,
                      wih_h + (size_t)(HDIM + j0)*HDIM + PDIM,
                      wih_h + (size_t)(2*HDIM + j0)*HDIM + PDIM, HDIM, PDIM/32, lane);
            const int j  = j0 + (lane & 15);
            const int r0 = wv*16 + ((lane >> 4) << 2);
            #pragma unroll
            for (int r = 0; r < 4; ++r) {
                const int b = r0 + r;
                const float rg = 1.f / (1.f + __expf(-(gir[r] + ghr[r] + bsr)));
                const float zg = 1.f / (1.f + __expf(-(giz[r] + ghz[r] + bsz)));
                const float e2 = __expf(2.f * ((gin_[r] + bin_) + rg * (ghn_[r] + bhn)));
                const float ng = 1.f - 2.f / (e2 + 1.f);        // tanh
                float hv = (1.f - zg) * ng + zg * hp[r];
                if (lenb[r] <= t) hv = 0.f;
                hp[r] = hv;
                out[(size_t)t*BATCH*HDIM + (size_t)b*HDIM + j] = hv;
                h_h[(size_t)b*HDIM + j] = (_Float16)hv;
                if (t == S_LEN - 1)
                    out[(size_t)S_LEN*BATCH*HDIM + (size_t)b*HDIM + j] = hv;  // h_last
            }
        }
        if (t < S_LEN - 1) gbar(arrive, gen, tid, blk);   // barrier H: h ready
    }
}

extern "C" void kernel_launch(void* const* d_in, const int* in_sizes, int n_in,
                              void* d_out, int out_size, void* d_ws, size_t ws_size,
                              hipStream_t stream) {
    (void)in_sizes; (void)n_in; (void)out_size; (void)ws_size;
    const float* incoming    = (const float*)d_in[0];
    const float* post        = (const float*)d_in[1];
    const float* h_init      = (const float*)d_in[2];
    const float* w_ih        = (const float*)d_in[3];
    const float* w_hh        = (const float*)d_in[4];
    const float* b_ih        = (const float*)d_in[5];
    const float* b_hh        = (const float*)d_in[6];
    const float* wq          = (const float*)d_in[7];
    const float* bq          = (const float*)d_in[8];
    const int*   length      = (const int*)d_in[9];
    const int*   post_length = (const int*)d_in[10];
    float* out = (float*)d_out;

    init_ctrl<<<96, 256, 0, stream>>>((unsigned*)d_ws);
    gru_main<<<NBLK, NTHR, 0, stream>>>(incoming, post, h_init, w_ih, w_hh, b_ih, b_hh,
                                        wq, bq, length, post_length, out, (char*)d_ws);
}

// Round 4
// 5818.207 us; speedup vs baseline: 1.4989x; 1.4989x over previous
//
#include <hip/hip_runtime.h>

// ---------------- problem dims ----------------
#define S_LEN 128
#define BATCH 64
#define EDIM  512
#define PLEN  160
#define PDIM  512
#define HDIM  1024
#define G3    3072      // 3*H
#define NBLK  128       // 64 gate blocks + 64 attention blocks (1 per batch)
#define NTHR  256
#define PROWS 144       // post rows resident in LDS; rows 144..159 streamed from L2

typedef _Float16 half8v  __attribute__((ext_vector_type(8)));
typedef _Float16 half4v  __attribute__((ext_vector_type(4)));
typedef _Float16 half2v  __attribute__((ext_vector_type(2)));
typedef float    f32x4   __attribute__((ext_vector_type(4)));

// ---------------- workspace layout (bytes) ----------------
// ctrl: arrive flags 128 slots @ stride 32 uints; qflag 32 slots @ stride 32
#define CTRL_UINTS 24576
#define OFF_CTRL ((size_t)0)                                  // 96 KiB
#define OFF_WIH  ((size_t)(CTRL_UINTS*4))                     // fp16 [3072][1024]
#define OFF_WHH  (OFF_WIH  + (size_t)G3*HDIM*2)               // fp16 [3072][1024]
#define OFF_WQH  (OFF_WHH  + (size_t)G3*HDIM*2)               // fp16 [512][1024]
#define OFF_INC  (OFF_WQH  + (size_t)PDIM*HDIM*2)             // fp16 [128][64][512]
#define OFF_POST (OFF_INC  + (size_t)S_LEN*BATCH*EDIM*2)      // fp16 [160][64][512]
#define OFF_HH   (OFF_POST + (size_t)PLEN*BATCH*PDIM*2)       // fp16 [64][1024]
#define OFF_QH   (OFF_HH   + (size_t)BATCH*HDIM*2)            // fp16 [64][512]
#define OFF_CTX  (OFF_QH   + (size_t)BATCH*PDIM*2)            // fp16 [64][512]
// total ~31 MB

__global__ void init_ctrl(unsigned* u) {
    int i = threadIdx.x + blockIdx.x * blockDim.x;
    if (i < CTRL_UINTS) u[i] = 0u;
}

__device__ __forceinline__ float wave_sum(float v) {
    v += __shfl_xor(v, 32); v += __shfl_xor(v, 16); v += __shfl_xor(v, 8);
    v += __shfl_xor(v, 4);  v += __shfl_xor(v, 2);  v += __shfl_xor(v, 1);
    return v;
}
__device__ __forceinline__ float wave_max(float v) {
    v = fmaxf(v, __shfl_xor(v, 32)); v = fmaxf(v, __shfl_xor(v, 16));
    v = fmaxf(v, __shfl_xor(v, 8));  v = fmaxf(v, __shfl_xor(v, 4));
    v = fmaxf(v, __shfl_xor(v, 2));  v = fmaxf(v, __shfl_xor(v, 1));
    return v;
}

// One-hop grid barrier: every block release-stores its padded flag, then 128
// threads of every block each poll one flag directly. Per-thread ACQUIRE on
// the observed flag provides the L1/L2 invalidate before post-barrier reads.
__device__ __forceinline__ void gbar(unsigned* arrive, unsigned& gen, int tid, int blk) {
    gen++;
    __syncthreads();   // drains vmcnt before s_barrier -> all block stores in L2
    if (tid == 0)
        __hip_atomic_store(&arrive[blk * 32], gen, __ATOMIC_RELEASE, __HIP_MEMORY_SCOPE_AGENT);
    if (tid < NBLK) {
        unsigned* fl = &arrive[tid * 32];
        while (__hip_atomic_load(fl, __ATOMIC_RELAXED, __HIP_MEMORY_SCOPE_AGENT) < gen)
            __builtin_amdgcn_s_sleep(1);
        __hip_atomic_load(fl, __ATOMIC_ACQUIRE, __HIP_MEMORY_SCOPE_AGENT);
    }
    __syncthreads();
}

// one 16x16 output tile accumulation: D[m,n] += sum_k A[m,k] * W[n,k]
__device__ __forceinline__ void mfma_acc(f32x4& acc, const _Float16* __restrict__ A, int lda,
                                         const _Float16* __restrict__ Bb, int ldb,
                                         int ksteps, int lane) {
    const _Float16* ap = A  + (size_t)(lane & 15) * lda + ((lane >> 4) << 3);
    const _Float16* bp = Bb + (size_t)(lane & 15) * ldb + ((lane >> 4) << 3);
    #pragma unroll
    for (int ks = 0; ks < ksteps; ++ks) {
        half8v av = *(const half8v*)ap;
        half8v bv = *(const half8v*)bp;
        acc = __builtin_amdgcn_mfma_f32_16x16x32_f16(av, bv, acc, 0, 0, 0);
        ap += 32; bp += 32;
    }
}

// three output tiles sharing one A stream (r,z,n gate rows)
__device__ __forceinline__ void mfma_acc3(f32x4& a0, f32x4& a1, f32x4& a2,
        const _Float16* __restrict__ A, int lda,
        const _Float16* __restrict__ B0, const _Float16* __restrict__ B1,
        const _Float16* __restrict__ B2, int ldb, int ksteps, int lane) {
    const _Float16* ap = A  + (size_t)(lane & 15) * lda + ((lane >> 4) << 3);
    const _Float16* p0 = B0 + (size_t)(lane & 15) * ldb + ((lane >> 4) << 3);
    const _Float16* p1 = B1 + (size_t)(lane & 15) * ldb + ((lane >> 4) << 3);
    const _Float16* p2 = B2 + (size_t)(lane & 15) * ldb + ((lane >> 4) << 3);
    #pragma unroll
    for (int ks = 0; ks < ksteps; ++ks) {
        half8v av = *(const half8v*)ap;
        a0 = __builtin_amdgcn_mfma_f32_16x16x32_f16(av, *(const half8v*)p0, a0, 0, 0, 0);
        a1 = __builtin_amdgcn_mfma_f32_16x16x32_f16(av, *(const half8v*)p1, a1, 0, 0, 0);
        a2 = __builtin_amdgcn_mfma_f32_16x16x32_f16(av, *(const half8v*)p2, a2, 0, 0, 0);
        ap += 32; p0 += 32; p1 += 32; p2 += 32;
    }
}

__global__ __launch_bounds__(NTHR, 1) void gru_main(
    const float* __restrict__ incoming, const float* __restrict__ post,
    const float* __restrict__ h_init,   const float* __restrict__ w_ih,
    const float* __restrict__ w_hh,     const float* __restrict__ b_ih,
    const float* __restrict__ b_hh,     const float* __restrict__ wq,
    const float* __restrict__ bq,       const int* __restrict__ length,
    const int* __restrict__ post_length, float* __restrict__ out,
    char* __restrict__ ws)
{
    const int tid  = threadIdx.x;
    const int blk  = blockIdx.x;
    const int lane = tid & 63;
    const int wv   = tid >> 6;

    unsigned* arrive = (unsigned*)(ws + OFF_CTRL);        // 128 x stride32
    unsigned* qflag  = (unsigned*)(ws + OFF_CTRL) + 4096; // 32 x stride32
    _Float16* wih_h  = (_Float16*)(ws + OFF_WIH);
    _Float16* whh_h  = (_Float16*)(ws + OFF_WHH);
    _Float16* wq_h   = (_Float16*)(ws + OFF_WQH);
    _Float16* inc_h  = (_Float16*)(ws + OFF_INC);
    _Float16* post_h = (_Float16*)(ws + OFF_POST);
    _Float16* h_h    = (_Float16*)(ws + OFF_HH);
    _Float16* query_h= (_Float16*)(ws + OFF_QH);
    _Float16* ctx_h  = (_Float16*)(ws + OFF_CTX);

    __shared__ _Float16 s_post[PROWS * PDIM];   // 144 KB: this batch's post rows 0..143
    __shared__ _Float16 s_q[PDIM];              // 1 KB
    __shared__ float s_scores[PLEN];
    __shared__ float s_w[PLEN];
    __shared__ float s_bc[2];

    unsigned gen = 0;

    // ---------------- per-block loop-invariant hoists ----------------
    float bsr = 0.f, bsz = 0.f, bin_ = 0.f, bhn = 0.f, bqv = 0.f;
    float hp[4] = {0.f, 0.f, 0.f, 0.f};
    int lenb[4] = {0, 0, 0, 0};
    int j0 = 0, ab = 0, plen = 0;
    if (blk < 64) {                       // gate block: owns h-cols j0..j0+15
        j0 = blk * 16;
        const int j = j0 + (lane & 15);
        bsr  = b_ih[j] + b_hh[j];
        bsz  = b_ih[HDIM + j] + b_hh[HDIM + j];
        bin_ = b_ih[2*HDIM + j];
        bhn  = b_hh[2*HDIM + j];
        if (blk < 32) bqv = bq[blk*16 + (lane & 15)];   // query producer
        const float hi = h_init[j];
        const int r0 = wv*16 + ((lane >> 4) << 2);
        #pragma unroll
        for (int r = 0; r < 4; ++r) { hp[r] = hi; lenb[r] = length[r0 + r]; }
    } else {                              // attention block: owns batch ab
        ab = blk - 64;
        plen = post_length[ab];
    }

    // ---------------- init: fp32 -> fp16 conversions (grid-strided) ----------------
    {
        const int NV4_W    = G3*HDIM/4;
        const int NV4_WQ   = PDIM*HDIM/4;
        const int NV4_INC  = S_LEN*BATCH*EDIM/4;
        const int NV4_POST = PLEN*BATCH*PDIM/4;
        const int TOT = 2*NV4_W + NV4_WQ + NV4_INC + NV4_POST;
        for (int i = blk*NTHR + tid; i < TOT; i += NBLK*NTHR) {
            const float* s; _Float16* dp; int o;
            if (i < NV4_W)                          { s = w_ih;     dp = wih_h;  o = i; }
            else if (i < 2*NV4_W)                   { s = w_hh;     dp = whh_h;  o = i - NV4_W; }
            else if (i < 2*NV4_W + NV4_WQ)          { s = wq;       dp = wq_h;   o = i - 2*NV4_W; }
            else if (i < 2*NV4_W + NV4_WQ + NV4_INC){ s = incoming; dp = inc_h;  o = i - 2*NV4_W - NV4_WQ; }
            else                                    { s = post;     dp = post_h; o = i - 2*NV4_W - NV4_WQ - NV4_INC; }
            f32x4 v = *(const f32x4*)(s + (size_t)o*4);
            half4v hv4 = {(_Float16)v.x, (_Float16)v.y, (_Float16)v.z, (_Float16)v.w};
            *(half4v*)(dp + (size_t)o*4) = hv4;
        }
        for (int i = blk*NTHR + tid; i < BATCH*HDIM; i += NBLK*NTHR)
            h_h[i] = (_Float16)h_init[i & (HDIM-1)];
    }
    // attention blocks: stage post rows 0..PROWS-1 of own batch into LDS (from fp32 input)
    if (blk >= 64) {
        for (int i = tid; i < PROWS*PDIM; i += NTHR) {
            const int p = i >> 9, d = i & (PDIM-1);
            s_post[i] = (_Float16)post[((size_t)p*BATCH + ab)*PDIM + d];
        }
    }
    gbar(arrive, gen, tid, blk);   // weights/inc/post/h ready

    // ---------------- time loop: 2 grid barriers per step ----------------
    for (int t = 0; t < S_LEN; ++t) {
        f32x4 ghr = {0.f,0.f,0.f,0.f}, ghz = {0.f,0.f,0.f,0.f}, ghn_ = {0.f,0.f,0.f,0.f};
        f32x4 gir = {0.f,0.f,0.f,0.f}, giz = {0.f,0.f,0.f,0.f}, gin_ = {0.f,0.f,0.f,0.f};

        if (blk < 64) {
            // ==== P1 gate: query FIRST (blocks 0..31), release flag, then gh/gi_x ====
            if (blk < 32) {
                const int q0 = blk * 16;
                f32x4 qa = {0.f,0.f,0.f,0.f};
                mfma_acc(qa, h_h + (size_t)(wv*16)*HDIM, HDIM,
                         wq_h + (size_t)q0*HDIM, HDIM, HDIM/32, lane);
                const int q  = q0 + (lane & 15);
                const int r0 = wv*16 + ((lane >> 4) << 2);
                #pragma unroll
                for (int r = 0; r < 4; ++r)
                    query_h[(size_t)(r0+r)*PDIM + q] = (_Float16)(qa[r] + bqv);
                __syncthreads();   // all waves' query stores drained (vmcnt0)
                if (tid == 0)
                    __hip_atomic_store(&qflag[blk * 32], (unsigned)(t+1),
                                       __ATOMIC_RELEASE, __HIP_MEMORY_SCOPE_AGENT);
            }
            // gh = h@Whh^T (r,z,n); gi_x = x_t@Wih[:, :512]^T — accumulators stay
            // in registers across barrier W (no staging buffers)
            mfma_acc3(ghr, ghz, ghn_, h_h + (size_t)(wv*16)*HDIM, HDIM,
                      whh_h + (size_t)j0*HDIM,
                      whh_h + (size_t)(HDIM + j0)*HDIM,
                      whh_h + (size_t)(2*HDIM + j0)*HDIM, HDIM, HDIM/32, lane);
            mfma_acc3(gir, giz, gin_, inc_h + ((size_t)t*BATCH + wv*16)*EDIM, EDIM,
                      wih_h + (size_t)j0*HDIM,
                      wih_h + (size_t)(HDIM + j0)*HDIM,
                      wih_h + (size_t)(2*HDIM + j0)*HDIM, HDIM, EDIM/32, lane);
        } else {
            // ==== P1 attention for batch ab: scores = post . query, softmax, ctx ====
            // prefetch streamed rows (independent of query) before the flag wait
            half8v srow[4];
            #pragma unroll
            for (int i = 0; i < 4; ++i)
                srow[i] = *(const half8v*)(post_h +
                            ((size_t)(PROWS + wv + 4*i)*BATCH + ab)*PDIM + lane*8);
            // wait for query producers (32 flags, written early in gate P1)
            if (tid < 32) {
                unsigned* fl = &qflag[tid * 32];
                while (__hip_atomic_load(fl, __ATOMIC_RELAXED, __HIP_MEMORY_SCOPE_AGENT) < (unsigned)(t+1))
                    __builtin_amdgcn_s_sleep(1);
                __hip_atomic_load(fl, __ATOMIC_ACQUIRE, __HIP_MEMORY_SCOPE_AGENT);
            }
            __syncthreads();
            if (tid < PDIM/8)
                *(half8v*)&s_q[tid*8] = *(const half8v*)&query_h[(size_t)ab*PDIM + tid*8];
            __syncthreads();
            const half8v qv = *(const half8v*)&s_q[lane*8];
            #pragma unroll 2
            for (int p = wv; p < PROWS; p += 4) {
                const half8v pv = *(const half8v*)&s_post[(size_t)p*PDIM + lane*8];
                float sd = 0.f;
                #pragma unroll
                for (int jj = 0; jj < 8; ++jj) sd += (float)pv[jj] * (float)qv[jj];
                sd = wave_sum(sd);
                if (lane == 0) s_scores[p] = sd;
            }
            #pragma unroll
            for (int i = 0; i < 4; ++i) {
                const half8v pv = srow[i];
                float sd = 0.f;
                #pragma unroll
                for (int jj = 0; jj < 8; ++jj) sd += (float)pv[jj] * (float)qv[jj];
                sd = wave_sum(sd);
                if (lane == 0) s_scores[PROWS + wv + 4*i] = sd;
            }
            __syncthreads();
            if (wv == 0) {
                float m = -1e30f;
                for (int p = lane; p < plen; p += 64) m = fmaxf(m, s_scores[p]);
                m = wave_max(m);
                if (lane == 0) s_bc[0] = m;
            }
            __syncthreads();
            const float mx = s_bc[0];
            if (tid < PLEN) s_w[tid] = (tid < plen) ? __expf(s_scores[tid] - mx) : 0.f;
            __syncthreads();
            if (wv == 0) {
                float ss = 0.f;
                for (int p = lane; p < PLEN; p += 64) ss += s_w[p];
                ss = wave_sum(ss);
                if (lane == 0) s_bc[1] = 1.f / ss;
            }
            __syncthreads();
            const float inv_den = s_bc[1];
            // ctx[d0,d0+1]: LDS rows then streamed rows (L1/L2-hot from score pass)
            const int d0 = tid << 1;
            float ca = 0.f, cb = 0.f;
            #pragma unroll 4
            for (int p = 0; p < PROWS; ++p) {
                const half2v pv2 = *(const half2v*)&s_post[(size_t)p*PDIM + d0];
                const float wp = s_w[p];
                ca += wp * (float)pv2[0];
                cb += wp * (float)pv2[1];
            }
            #pragma unroll 4
            for (int p = PROWS; p < PLEN; ++p) {
                const half2v pv2 = *(const half2v*)(post_h + ((size_t)p*BATCH + ab)*PDIM + d0);
                const float wp = s_w[p];
                ca += wp * (float)pv2[0];
                cb += wp * (float)pv2[1];
            }
            half2v cv; cv[0] = (_Float16)(ca * inv_den); cv[1] = (_Float16)(cb * inv_den);
            *(half2v*)&ctx_h[(size_t)ab*PDIM + d0] = cv;
        }
        gbar(arrive, gen, tid, blk);   // barrier W: ctx ready

        if (blk < 64) {
            // ==== P2 gate: gi += ctx@Wih[:, 512:]^T, gate math, h update ====
            mfma_acc3(gir, giz, gin_, ctx_h + (size_t)(wv*16)*PDIM, PDIM,
                      wih_h + (size_t)j0*HDIM + PDIM,
                      wih_h + (size_t)(HDIM + j0)*HDIM + PDIM,
                      wih_h + (size_t)(2*HDIM + j0)*HDIM + PDIM, HDIM, PDIM/32, lane);
            const int j  = j0 + (lane & 15);
            const int r0 = wv*16 + ((lane >> 4) << 2);
            #pragma unroll
            for (int r = 0; r < 4; ++r) {
                const int b = r0 + r;
                const float rg = 1.f / (1.f + __expf(-(gir[r] + ghr[r] + bsr)));
                const float zg = 1.f / (1.f + __expf(-(giz[r] + ghz[r] + bsz)));
                const float e2 = __expf(2.f * ((gin_[r] + bin_) + rg * (ghn_[r] + bhn)));
                const float ng = 1.f - 2.f / (e2 + 1.f);        // tanh
                float hv = (1.f - zg) * ng + zg * hp[r];
                if (lenb[r] <= t) hv = 0.f;
                hp[r] = hv;
                out[(size_t)t*BATCH*HDIM + (size_t)b*HDIM + j] = hv;
                h_h[(size_t)b*HDIM + j] = (_Float16)hv;
                if (t == S_LEN - 1)
                    out[(size_t)S_LEN*BATCH*HDIM + (size_t)b*HDIM + j] = hv;  // h_last
            }
        }
        if (t < S_LEN - 1) gbar(arrive, gen, tid, blk);   // barrier H: h ready
    }
}

extern "C" void kernel_launch(void* const* d_in, const int* in_sizes, int n_in,
                              void* d_out, int out_size, void* d_ws, size_t ws_size,
                              hipStream_t stream) {
    (void)in_sizes; (void)n_in; (void)out_size; (void)ws_size;
    const float* incoming    = (const float*)d_in[0];
    const float* post        = (const float*)d_in[1];
    const float* h_init      = (const float*)d_in[2];
    const float* w_ih        = (const float*)d_in[3];
    const float* w_hh        = (const float*)d_in[4];
    const float* b_ih        = (const float*)d_in[5];
    const float* b_hh        = (const float*)d_in[6];
    const float* wq          = (const float*)d_in[7];
    const float* bq          = (const float*)d_in[8];
    const int*   length      = (const int*)d_in[9];
    const int*   post_length = (const int*)d_in[10];
    float* out = (float*)d_out;

    init_ctrl<<<96, 256, 0, stream>>>((unsigned*)d_ws);
    gru_main<<<NBLK, NTHR, 0, stream>>>(incoming, post, h_init, w_ih, w_hh, b_ih, b_hh,
                                        wq, bq, length, post_length, out, (char*)d_ws);
}